// Round 7
// baseline (317.663 us; speedup 1.0000x reference)
//
#include <hip/hip_runtime.h>

// Problem constants.
#define B_SZ 16384
#define C_SZ 4096
#define D_SZ 512

// Re-rank threshold in "dist units" (raw_l2/2). bf16 hi*hi dot error sigma
// ~= 0.07; max approx err ~0.4; key quantization (6 bits masked at value
// ~2^10) ~0.008. 2*0.4 + 0.02 < 1.0 = EPS.
#define EPS 1.0f
// Bias making dist' = BIAS + 0.5*csq - dot strictly positive (needs
// BIAS > 0.5*xsq; xsq ~ chi2(512) <= ~700 at 14 sigma).
#define DBIAS 1024.0f

typedef __attribute__((ext_vector_type(8))) short short8;   // 8 bf16 = 4 VGPRs
typedef __attribute__((ext_vector_type(4))) float floatx4;  // MFMA acc

// ---- helpers ---------------------------------------------------------------
__device__ inline unsigned short f2bf(float f) {
    unsigned u = __float_as_uint(f);
    unsigned r = u + 0x7FFFu + ((u >> 16) & 1u);   // round-to-nearest-even
    return (unsigned short)(r >> 16);
}
__device__ inline void gload16(const void* g, void* l) {
    // async global->LDS, 16B/lane; LDS dest = wave-uniform base + lane*16
    __builtin_amdgcn_global_load_lds(
        (const __attribute__((address_space(1))) void*)g,
        (__attribute__((address_space(3))) void*)l, 16, 0, 0);
}

// ---------------------------------------------------------------------------
// Prep (fused): x -> bf16 hi plane; codes -> bf16 hi plane + c_sq (fp32).
// Blocks [0, 8192): x elements. Blocks [8192, 9216): one wave per code row.
// Also zeroes the last-block completion counter used by rerank.
// ---------------------------------------------------------------------------
__global__ __launch_bounds__(256) void convert_kernel(const float* __restrict__ x,
                                                      const float* __restrict__ codes,
                                                      unsigned short* __restrict__ xhi,
                                                      unsigned short* __restrict__ chi,
                                                      float* __restrict__ csq,
                                                      unsigned* __restrict__ counter) {
    const int XB = (B_SZ * D_SZ) / 4 / 256;   // 8192
    if (blockIdx.x == 0 && threadIdx.x == 0) *counter = 0u;
    if (blockIdx.x < XB) {
        const int tid = blockIdx.x * 256 + threadIdx.x;
        const float4 v = ((const float4*)x)[tid];
        ((ushort4*)xhi)[tid] = make_ushort4(f2bf(v.x), f2bf(v.y), f2bf(v.z), f2bf(v.w));
    } else {
        const int t = threadIdx.x;
        const int wave = t >> 6;
        const int lane = t & 63;
        const int code = (blockIdx.x - XB) * 4 + wave;
        const float4* cp = (const float4*)(codes + (size_t)code * D_SZ);
        float s = 0.0f;
        #pragma unroll
        for (int u = 0; u < 2; ++u) {
            const float4 v = cp[lane + 64 * u];
            ((ushort4*)chi)[(size_t)code * (D_SZ / 4) + lane + 64 * u] =
                make_ushort4(f2bf(v.x), f2bf(v.y), f2bf(v.z), f2bf(v.w));
            s = fmaf(v.x, v.x, s); s = fmaf(v.y, v.y, s);
            s = fmaf(v.z, v.z, s); s = fmaf(v.w, v.w, s);
        }
        #pragma unroll
        for (int off = 32; off; off >>= 1) s += __shfl_down(s, off, 64);
        if (lane == 0) csq[code] = s;
    }
}

// ---------------------------------------------------------------------------
// Main: hi*hi bf16 MFMA GEMM, 128x128 block tile, 8 waves (512 thr), wave =
// 32 rows x 64 cols (acc = 8 tiles = 32 AGPR). VGPR 44 + AGPR 32 = 76 regs
// <= 512/6 -> __launch_bounds__(512,6) allows 3 blocks/CU (24 waves) for
// cross-block hiding of the per-kt barrier drains.
// BK=64, XOR-swizzled LDS (16B chunk' = chunk ^ (row&7)), zero conflicts.
// Epilogue: dist' = (DBIAS + 0.5*csq) - dot > 0 -> raw float bits are
// order-monotone; key = (bits & ~63) | (col low 6 bits). Top-2 of 4 via
// min/max network, 4-step u32 16-lane merge, one uint2 store per
// (row, 64-col half). NO atomics.
// ---------------------------------------------------------------------------
__global__ __launch_bounds__(512, 6) void gemm_argmin_kernel(
        const unsigned short* __restrict__ xhi,
        const unsigned short* __restrict__ chi,
        const float* __restrict__ csq,
        uint2* __restrict__ table) {
    __shared__ unsigned short sA[128][64];   // 16 KB
    __shared__ unsigned short sB[128][64];   // 16 KB

    const int t = threadIdx.x;
    const int wave = t >> 6;     // 0..7
    const int lane = t & 63;
    const int quad = lane >> 4;
    const int l15 = lane & 15;

    const int rowbase = blockIdx.y * 128;   // x rows
    const int colbase = blockIdx.x * 128;   // code cols
    const int wr = (wave >> 1) * 32;        // wave's 32-row strip
    const int wc = (wave & 1) * 64;         // wave's 64-col half

    // staging: waves 0-3 stage A rows w*32..+32; waves 4-7 stage B similarly.
    // 4 gload16 per wave per kt, 8 rows per inst.
    const unsigned short* gsrc;
    unsigned short(*ltile)[64];
    int rowoff;
    if (wave < 4) { gsrc = xhi + (size_t)rowbase * D_SZ; ltile = sA; rowoff = wave * 32; }
    else          { gsrc = chi + (size_t)colbase * D_SZ; ltile = sB; rowoff = (wave - 4) * 32; }
    const int lrow = lane >> 3;                       // 0..7 within 8-row group
    const int lchunk = (lane & 7) ^ (lrow & 7);       // swizzled 16B-chunk source
    const unsigned short* gbase = gsrc + (size_t)(rowoff + lrow) * D_SZ + lchunk * 8;

    // epilogue csq terms, loaded up front (L2-resident)
    float cs2[4];
    #pragma unroll
    for (int j = 0; j < 4; ++j)
        cs2[j] = fmaf(0.5f, csq[colbase + wc + j * 16 + l15], DBIAS);

    floatx4 acc[2][4];
    #pragma unroll
    for (int i = 0; i < 2; ++i)
        #pragma unroll
        for (int j = 0; j < 4; ++j) acc[i][j] = (floatx4)0.0f;

    for (int kt = 0; kt < D_SZ / 64; ++kt) {
        const unsigned short* g = gbase + kt * 64;
        #pragma unroll
        for (int inst = 0; inst < 4; ++inst)
            gload16(g + (size_t)(inst * 8) * D_SZ, &ltile[rowoff + inst * 8][0]);
        __syncthreads();

        #pragma unroll
        for (int ksub = 0; ksub < 2; ++ksub) {
            const int cc = ((ksub * 4 + quad) ^ (l15 & 7)) * 8;
            short8 a[2], b[4];
            #pragma unroll
            for (int i = 0; i < 2; ++i)
                a[i] = *(const short8*)&sA[wr + i * 16 + l15][cc];
            #pragma unroll
            for (int j = 0; j < 4; ++j)
                b[j] = *(const short8*)&sB[wc + j * 16 + l15][cc];
            #pragma unroll
            for (int i = 0; i < 2; ++i)
                #pragma unroll
                for (int j = 0; j < 4; ++j)
                    acc[i][j] = __builtin_amdgcn_mfma_f32_16x16x32_bf16(a[i], b[j], acc[i][j], 0, 0, 0);
        }
        __syncthreads();
    }

    // ---- epilogue: packed-key top-2 per (row, this wave's 64-col half)
    const int hb = blockIdx.x * 2 + (wave & 1);   // 64-col half index, 0..63

    #pragma unroll
    for (int i = 0; i < 2; ++i) {
        #pragma unroll
        for (int r = 0; r < 4; ++r) {
            unsigned k[4];
            #pragma unroll
            for (int j = 0; j < 4; ++j) {
                const float d = cs2[j] - acc[i][j][r];   // > 0 by DBIAS
                k[j] = (__float_as_uint(d) & 0xFFFFFFC0u) | (unsigned)(j * 16 + l15);
            }
            // top-2-of-4 min/max network
            const unsigned lo1 = min(k[0], k[1]), hi1 = max(k[0], k[1]);
            const unsigned lo2 = min(k[2], k[3]), hi2 = max(k[2], k[3]);
            unsigned k1 = min(lo1, lo2);
            unsigned k2 = min(max(lo1, lo2), min(hi1, hi2));
            // 16-lane top-2 merge
            #pragma unroll
            for (int off = 8; off; off >>= 1) {
                const unsigned ok1 = (unsigned)__shfl_down((int)k1, off, 16);
                const unsigned ok2 = (unsigned)__shfl_down((int)k2, off, 16);
                const unsigned hi = max(k1, ok1);
                const unsigned w2 = (k1 < ok1) ? k2 : ok2;
                k1 = min(k1, ok1);
                k2 = min(hi, w2);
            }
            if (l15 == 0) {
                const int grow = rowbase + wr + i * 16 + quad * 4 + r;
                table[(size_t)grow * 64 + hb] = make_uint2(k1, k2);
            }
        }
    }
}

// ---------------------------------------------------------------------------
// Re-rank + gather + loss (+ last-block final loss reduce). One wave per row.
// Keys are positive-float bits; col = 64*lane + (key & 63). If a single
// candidate <= min+EPS it is the exact argmin; else exact fp32 re-rank.
// ---------------------------------------------------------------------------
__global__ __launch_bounds__(256) void rerank_gather_loss_kernel(
        const float* __restrict__ x,
        const float* __restrict__ codes,
        const float* __restrict__ csq,
        const uint2* __restrict__ table,
        float* __restrict__ outq,
        float* __restrict__ out_idx_f,
        float* __restrict__ partials,
        unsigned* __restrict__ counter,
        float* __restrict__ loss_slot) {
    __shared__ float red[4];
    const int t = threadIdx.x;
    const int wave = t >> 6;
    const int lane = t & 63;
    const int row = blockIdx.x * 4 + wave;

    const uint2 e = table[(size_t)row * 64 + lane];
    const unsigned k1 = e.x, k2 = e.y;

    // wave min over the 64 half-best keys
    unsigned mk = k1;
    #pragma unroll
    for (int off = 32; off; off >>= 1)
        mk = min(mk, (unsigned)__shfl_xor((int)mk, off, 64));

    const float thr = __uint_as_float(mk & 0xFFFFFFC0u) + EPS;
    const float v1 = __uint_as_float(k1 & 0xFFFFFFC0u);
    const float v2 = __uint_as_float(k2 & 0xFFFFFFC0u);
    const unsigned long long b1 = __ballot(v1 <= thr);
    const unsigned long long b2 = __ballot(v2 <= thr);

    // default argmin: lowest lane (= lowest half = lowest col) holding mk
    const unsigned long long bm = __ballot(k1 == mk);
    const int mhb = __ffsll(bm) - 1;
    int fin = mhb * 64 + (int)(mk & 63u);

    // x row: 8 floats/lane
    const float4* xp = (const float4*)(x + (size_t)row * D_SZ);
    const float4 x0 = xp[lane];
    const float4 x1 = xp[lane + 64];

    if (__popcll(b1) + __popcll(b2) > 1) {
        const int c1 = lane * 64 + (int)(k1 & 63u);
        const int c2 = lane * 64 + (int)(k2 & 63u);
        float bv = 3.4e38f; int bi = 0x7FFFFFFF;
        #pragma unroll
        for (int pass = 0; pass < 2; ++pass) {
            unsigned long long bb = pass ? b2 : b1;
            const int myc = pass ? c2 : c1;
            while (bb) {
                const int src = __ffsll((unsigned long long)bb) - 1;
                bb &= bb - 1;
                const int ci = __shfl(myc, src, 64);
                const float4* cp = (const float4*)(codes + (size_t)ci * D_SZ);
                const float4 c0 = cp[lane];
                const float4 c1v = cp[lane + 64];
                float s = 0.0f;
                s = fmaf(x0.x, c0.x, s); s = fmaf(x0.y, c0.y, s);
                s = fmaf(x0.z, c0.z, s); s = fmaf(x0.w, c0.w, s);
                s = fmaf(x1.x, c1v.x, s); s = fmaf(x1.y, c1v.y, s);
                s = fmaf(x1.z, c1v.z, s); s = fmaf(x1.w, c1v.w, s);
                #pragma unroll
                for (int off = 32; off; off >>= 1) s += __shfl_xor(s, off, 64);
                const float d = fmaf(0.5f, csq[ci], -s);   // 0.5*csq - dot (exact fp32)
                if (d < bv || (d == bv && ci < bi)) { bv = d; bi = ci; }
            }
        }
        fin = bi;
    }

    // gather + loss partial
    const float4* qp = (const float4*)(codes + (size_t)fin * D_SZ);
    float4* op = (float4*)(outq + (size_t)row * D_SZ);
    const float4 q0 = qp[lane];
    const float4 q1 = qp[lane + 64];
    op[lane] = q0;
    op[lane + 64] = q1;
    float s = 0.0f;
    {
        const float d0 = x0.x - q0.x, d1 = x0.y - q0.y, d2 = x0.z - q0.z, d3 = x0.w - q0.w;
        const float d4 = x1.x - q1.x, d5 = x1.y - q1.y, d6 = x1.z - q1.z, d7 = x1.w - q1.w;
        s = d0 * d0 + d1 * d1 + d2 * d2 + d3 * d3 + d4 * d4 + d5 * d5 + d6 * d6 + d7 * d7;
    }
    #pragma unroll
    for (int off = 32; off; off >>= 1) s += __shfl_down(s, off, 64);
    if (lane == 0) {
        red[wave] = s;
        out_idx_f[row] = (float)fin;
    }
    __syncthreads();

    // publish partial; last block to finish reduces all partials -> loss.
    __shared__ bool amlast;
    if (t == 0) {
        partials[blockIdx.x] = red[0] + red[1] + red[2] + red[3];
        __threadfence();                               // release partial
        const unsigned old = atomicAdd(counter, 1u);   // device-scope
        amlast = (old == (unsigned)(B_SZ / 4 - 1));
    }
    __syncthreads();
    if (amlast) {
        __threadfence();                               // acquire others' partials
        float ls = 0.0f;
        #pragma unroll
        for (int i = 0; i < (B_SZ / 4) / 256; ++i) ls += partials[i * 256 + t];
        #pragma unroll
        for (int off = 32; off; off >>= 1) ls += __shfl_down(ls, off, 64);
        if (lane == 0) red[wave] = ls;
        __syncthreads();
        if (t == 0)
            *loss_slot = (red[0] + red[1] + red[2] + red[3]) * (1.25f / (float)B_SZ);
    }
}

// ---------------------------------------------------------------------------
extern "C" void kernel_launch(void* const* d_in, const int* in_sizes, int n_in,
                              void* d_out, int out_size, void* d_ws, size_t ws_size,
                              hipStream_t stream) {
    const float* x = (const float*)d_in[0];
    const float* codes = (const float*)d_in[1];  // (1, C, D) contiguous

    float* outq = (float*)d_out;                       // [B*D]
    float* out_idx_f = outq + (size_t)B_SZ * D_SZ;     // [B]
    float* loss_slot = out_idx_f + B_SZ;               // [1]

    // workspace: xhi 16M | chi 4M | csq 16K | table 8M (uint2) | partials 16K | counter
    unsigned short* xhi = (unsigned short*)d_ws;
    unsigned short* chi = xhi + (size_t)B_SZ * D_SZ;
    float* csq = (float*)(chi + (size_t)C_SZ * D_SZ);
    uint2* table = (uint2*)(csq + C_SZ);
    float* partials = (float*)(table + (size_t)B_SZ * 64);
    unsigned* counter = (unsigned*)(partials + B_SZ / 4);

    const int XB = (B_SZ * D_SZ) / 4 / 256;           // 8192
    const int CB = C_SZ / 4;                          // 1024
    convert_kernel<<<XB + CB, 256, 0, stream>>>(x, codes, xhi, chi, csq, counter);
    gemm_argmin_kernel<<<dim3(C_SZ / 128, B_SZ / 128), 512, 0, stream>>>(xhi, chi, csq, table);
    rerank_gather_loss_kernel<<<B_SZ / 4, 256, 0, stream>>>(x, codes, csq, table, outq, out_idx_f,
                                                            partials, counter, loss_slot);
}

// Round 8
// 188.582 us; speedup vs baseline: 1.6845x; 1.6845x over previous
//
#include <hip/hip_runtime.h>

// Problem constants.
#define B_SZ 16384
#define C_SZ 4096
#define D_SZ 512

// Re-rank threshold in "dist units" (raw_l2/2). bf16 hi*hi dot error sigma
// ~= 0.07; max approx err ~0.4; key quantization (6 bits masked at value
// ~2^10) ~0.008. 2*0.4 + 0.02 < 1.0 = EPS.
#define EPS 1.0f
// Bias making dist' = BIAS + 0.5*csq - dot strictly positive (needs
// BIAS > 0.5*xsq; xsq ~ chi2(512) <= ~700 at 14 sigma).
#define DBIAS 1024.0f

typedef __attribute__((ext_vector_type(8))) short short8;   // 8 bf16 = 4 VGPRs
typedef __attribute__((ext_vector_type(4))) float floatx4;  // MFMA acc

// ---- helpers ---------------------------------------------------------------
__device__ inline unsigned short f2bf(float f) {
    unsigned u = __float_as_uint(f);
    unsigned r = u + 0x7FFFu + ((u >> 16) & 1u);   // round-to-nearest-even
    return (unsigned short)(r >> 16);
}
__device__ inline void gload16(const void* g, void* l) {
    // async global->LDS, 16B/lane; LDS dest = wave-uniform base + lane*16
    __builtin_amdgcn_global_load_lds(
        (const __attribute__((address_space(1))) void*)g,
        (__attribute__((address_space(3))) void*)l, 16, 0, 0);
}

// ---------------------------------------------------------------------------
// Prep (fused): x -> bf16 hi plane; codes -> bf16 hi plane + c_sq (fp32).
// Blocks [0, 8192): x elements. Blocks [8192, 9216): one wave per code row.
// ---------------------------------------------------------------------------
__global__ __launch_bounds__(256) void convert_kernel(const float* __restrict__ x,
                                                      const float* __restrict__ codes,
                                                      unsigned short* __restrict__ xhi,
                                                      unsigned short* __restrict__ chi,
                                                      float* __restrict__ csq) {
    const int XB = (B_SZ * D_SZ) / 4 / 256;   // 8192
    if (blockIdx.x < XB) {
        const int tid = blockIdx.x * 256 + threadIdx.x;
        const float4 v = ((const float4*)x)[tid];
        ((ushort4*)xhi)[tid] = make_ushort4(f2bf(v.x), f2bf(v.y), f2bf(v.z), f2bf(v.w));
    } else {
        const int t = threadIdx.x;
        const int wave = t >> 6;
        const int lane = t & 63;
        const int code = (blockIdx.x - XB) * 4 + wave;
        const float4* cp = (const float4*)(codes + (size_t)code * D_SZ);
        float s = 0.0f;
        #pragma unroll
        for (int u = 0; u < 2; ++u) {
            const float4 v = cp[lane + 64 * u];
            ((ushort4*)chi)[(size_t)code * (D_SZ / 4) + lane + 64 * u] =
                make_ushort4(f2bf(v.x), f2bf(v.y), f2bf(v.z), f2bf(v.w));
            s = fmaf(v.x, v.x, s); s = fmaf(v.y, v.y, s);
            s = fmaf(v.z, v.z, s); s = fmaf(v.w, v.w, s);
        }
        #pragma unroll
        for (int off = 32; off; off >>= 1) s += __shfl_down(s, off, 64);
        if (lane == 0) csq[code] = s;
    }
}

// ---------------------------------------------------------------------------
// Main: hi*hi bf16 MFMA GEMM, 128x128 block tile, 8 waves (512 thr), wave =
// 32 rows x 64 cols (acc = 8 tiles = 32 AGPR). VGPR 44 + AGPR 32 = 76 regs
// <= 512/6 -> __launch_bounds__(512,6) allows 3 blocks/CU (24 waves) for
// cross-block hiding of the per-kt barrier drains.
// BK=64, XOR-swizzled LDS (16B chunk' = chunk ^ (row&7)), zero conflicts.
// Epilogue: dist' = (DBIAS + 0.5*csq) - dot > 0 -> raw float bits are
// order-monotone; key = (bits & ~63) | (col low 6 bits). Top-2 of 4 via
// min/max network, 4-step u32 16-lane merge, one uint2 store per
// (row, 64-col half). NO atomics, NO fences.
// ---------------------------------------------------------------------------
__global__ __launch_bounds__(512, 6) void gemm_argmin_kernel(
        const unsigned short* __restrict__ xhi,
        const unsigned short* __restrict__ chi,
        const float* __restrict__ csq,
        uint2* __restrict__ table) {
    __shared__ unsigned short sA[128][64];   // 16 KB
    __shared__ unsigned short sB[128][64];   // 16 KB

    const int t = threadIdx.x;
    const int wave = t >> 6;     // 0..7
    const int lane = t & 63;
    const int quad = lane >> 4;
    const int l15 = lane & 15;

    const int rowbase = blockIdx.y * 128;   // x rows
    const int colbase = blockIdx.x * 128;   // code cols
    const int wr = (wave >> 1) * 32;        // wave's 32-row strip
    const int wc = (wave & 1) * 64;         // wave's 64-col half

    // staging: waves 0-3 stage A rows w*32..+32; waves 4-7 stage B similarly.
    const unsigned short* gsrc;
    unsigned short(*ltile)[64];
    int rowoff;
    if (wave < 4) { gsrc = xhi + (size_t)rowbase * D_SZ; ltile = sA; rowoff = wave * 32; }
    else          { gsrc = chi + (size_t)colbase * D_SZ; ltile = sB; rowoff = (wave - 4) * 32; }
    const int lrow = lane >> 3;                       // 0..7 within 8-row group
    const int lchunk = (lane & 7) ^ (lrow & 7);       // swizzled 16B-chunk source
    const unsigned short* gbase = gsrc + (size_t)(rowoff + lrow) * D_SZ + lchunk * 8;

    // epilogue csq terms, loaded up front (L2-resident)
    float cs2[4];
    #pragma unroll
    for (int j = 0; j < 4; ++j)
        cs2[j] = fmaf(0.5f, csq[colbase + wc + j * 16 + l15], DBIAS);

    floatx4 acc[2][4];
    #pragma unroll
    for (int i = 0; i < 2; ++i)
        #pragma unroll
        for (int j = 0; j < 4; ++j) acc[i][j] = (floatx4)0.0f;

    for (int kt = 0; kt < D_SZ / 64; ++kt) {
        const unsigned short* g = gbase + kt * 64;
        #pragma unroll
        for (int inst = 0; inst < 4; ++inst)
            gload16(g + (size_t)(inst * 8) * D_SZ, &ltile[rowoff + inst * 8][0]);
        __syncthreads();

        #pragma unroll
        for (int ksub = 0; ksub < 2; ++ksub) {
            const int cc = ((ksub * 4 + quad) ^ (l15 & 7)) * 8;
            short8 a[2], b[4];
            #pragma unroll
            for (int i = 0; i < 2; ++i)
                a[i] = *(const short8*)&sA[wr + i * 16 + l15][cc];
            #pragma unroll
            for (int j = 0; j < 4; ++j)
                b[j] = *(const short8*)&sB[wc + j * 16 + l15][cc];
            #pragma unroll
            for (int i = 0; i < 2; ++i)
                #pragma unroll
                for (int j = 0; j < 4; ++j)
                    acc[i][j] = __builtin_amdgcn_mfma_f32_16x16x32_bf16(a[i], b[j], acc[i][j], 0, 0, 0);
        }
        __syncthreads();
    }

    // ---- epilogue: packed-key top-2 per (row, this wave's 64-col half)
    const int hb = blockIdx.x * 2 + (wave & 1);   // 64-col half index, 0..63

    #pragma unroll
    for (int i = 0; i < 2; ++i) {
        #pragma unroll
        for (int r = 0; r < 4; ++r) {
            unsigned k[4];
            #pragma unroll
            for (int j = 0; j < 4; ++j) {
                const float d = cs2[j] - acc[i][j][r];   // > 0 by DBIAS
                k[j] = (__float_as_uint(d) & 0xFFFFFFC0u) | (unsigned)(j * 16 + l15);
            }
            // top-2-of-4 min/max network
            const unsigned lo1 = min(k[0], k[1]), hi1 = max(k[0], k[1]);
            const unsigned lo2 = min(k[2], k[3]), hi2 = max(k[2], k[3]);
            unsigned k1 = min(lo1, lo2);
            unsigned k2 = min(max(lo1, lo2), min(hi1, hi2));
            // 16-lane top-2 merge
            #pragma unroll
            for (int off = 8; off; off >>= 1) {
                const unsigned ok1 = (unsigned)__shfl_down((int)k1, off, 16);
                const unsigned ok2 = (unsigned)__shfl_down((int)k2, off, 16);
                const unsigned hi = max(k1, ok1);
                const unsigned w2 = (k1 < ok1) ? k2 : ok2;
                k1 = min(k1, ok1);
                k2 = min(hi, w2);
            }
            if (l15 == 0) {
                const int grow = rowbase + wr + i * 16 + quad * 4 + r;
                table[(size_t)grow * 64 + hb] = make_uint2(k1, k2);
            }
        }
    }
}

// ---------------------------------------------------------------------------
// Re-rank + gather + loss. FOUR rows per wave (4x memory-level parallelism:
// batch 4 table loads + 8 x loads, resolve 4 fins, then 8 independent gather
// loads). Keys are positive-float bits; col = 64*lane + (key & 63).
// ---------------------------------------------------------------------------
__global__ __launch_bounds__(256) void rerank_gather_loss_kernel(
        const float* __restrict__ x,
        const float* __restrict__ codes,
        const float* __restrict__ csq,
        const uint2* __restrict__ table,
        float* __restrict__ outq,
        float* __restrict__ out_idx_f,
        float* __restrict__ partials) {
    __shared__ float red[4];
    const int t = threadIdx.x;
    const int wave = t >> 6;
    const int lane = t & 63;
    const int row0 = (blockIdx.x * 4 + wave) * 4;   // 4 consecutive rows

    // ---- batched independent loads: 4 table entries + 4 x rows
    uint2 e[4];
    float4 xv[4][2];
    #pragma unroll
    for (int r = 0; r < 4; ++r) {
        e[r] = table[(size_t)(row0 + r) * 64 + lane];
        const float4* xp = (const float4*)(x + (size_t)(row0 + r) * D_SZ);
        xv[r][0] = xp[lane];
        xv[r][1] = xp[lane + 64];
    }

    // ---- resolve argmin per row
    int fin[4];
    #pragma unroll
    for (int r = 0; r < 4; ++r) {
        const unsigned k1 = e[r].x, k2 = e[r].y;
        unsigned mk = k1;
        #pragma unroll
        for (int off = 32; off; off >>= 1)
            mk = min(mk, (unsigned)__shfl_xor((int)mk, off, 64));

        const float thr = __uint_as_float(mk & 0xFFFFFFC0u) + EPS;
        const float v1 = __uint_as_float(k1 & 0xFFFFFFC0u);
        const float v2 = __uint_as_float(k2 & 0xFFFFFFC0u);
        const unsigned long long b1 = __ballot(v1 <= thr);
        const unsigned long long b2 = __ballot(v2 <= thr);

        const unsigned long long bm = __ballot(k1 == mk);
        fin[r] = (__ffsll(bm) - 1) * 64 + (int)(mk & 63u);

        if (__popcll(b1) + __popcll(b2) > 1) {       // rare exact fp32 re-rank
            const int c1 = lane * 64 + (int)(k1 & 63u);
            const int c2 = lane * 64 + (int)(k2 & 63u);
            float bv = 3.4e38f; int bi = 0x7FFFFFFF;
            #pragma unroll
            for (int pass = 0; pass < 2; ++pass) {
                unsigned long long bb = pass ? b2 : b1;
                const int myc = pass ? c2 : c1;
                while (bb) {
                    const int src = __ffsll((unsigned long long)bb) - 1;
                    bb &= bb - 1;
                    const int ci = __shfl(myc, src, 64);
                    const float4* cp = (const float4*)(codes + (size_t)ci * D_SZ);
                    const float4 c0 = cp[lane];
                    const float4 c1v = cp[lane + 64];
                    float s = 0.0f;
                    s = fmaf(xv[r][0].x, c0.x, s);  s = fmaf(xv[r][0].y, c0.y, s);
                    s = fmaf(xv[r][0].z, c0.z, s);  s = fmaf(xv[r][0].w, c0.w, s);
                    s = fmaf(xv[r][1].x, c1v.x, s); s = fmaf(xv[r][1].y, c1v.y, s);
                    s = fmaf(xv[r][1].z, c1v.z, s); s = fmaf(xv[r][1].w, c1v.w, s);
                    #pragma unroll
                    for (int off = 32; off; off >>= 1) s += __shfl_xor(s, off, 64);
                    const float d = fmaf(0.5f, csq[ci], -s);   // exact fp32
                    if (d < bv || (d == bv && ci < bi)) { bv = d; bi = ci; }
                }
            }
            fin[r] = bi;
        }
    }

    // ---- batched independent gathers
    float4 qv[4][2];
    #pragma unroll
    for (int r = 0; r < 4; ++r) {
        const float4* qp = (const float4*)(codes + (size_t)fin[r] * D_SZ);
        qv[r][0] = qp[lane];
        qv[r][1] = qp[lane + 64];
    }

    // ---- writes + loss partial
    float s = 0.0f;
    #pragma unroll
    for (int r = 0; r < 4; ++r) {
        float4* op = (float4*)(outq + (size_t)(row0 + r) * D_SZ);
        op[lane] = qv[r][0];
        op[lane + 64] = qv[r][1];
        const float d0 = xv[r][0].x - qv[r][0].x, d1 = xv[r][0].y - qv[r][0].y;
        const float d2 = xv[r][0].z - qv[r][0].z, d3 = xv[r][0].w - qv[r][0].w;
        const float d4 = xv[r][1].x - qv[r][1].x, d5 = xv[r][1].y - qv[r][1].y;
        const float d6 = xv[r][1].z - qv[r][1].z, d7 = xv[r][1].w - qv[r][1].w;
        s += d0 * d0 + d1 * d1 + d2 * d2 + d3 * d3 + d4 * d4 + d5 * d5 + d6 * d6 + d7 * d7;
        if (lane == 0) out_idx_f[row0 + r] = (float)fin[r];
    }
    #pragma unroll
    for (int off = 32; off; off >>= 1) s += __shfl_down(s, off, 64);
    if (lane == 0) red[wave] = s;
    __syncthreads();
    if (t == 0) partials[blockIdx.x] = red[0] + red[1] + red[2] + red[3];
}

// ---------------------------------------------------------------------------
// Loss: sum 1024 block partials -> loss_slot. One block.
// ---------------------------------------------------------------------------
__global__ __launch_bounds__(256) void loss_reduce_kernel(const float* __restrict__ partials,
                                                          float* __restrict__ loss_slot) {
    __shared__ float red[4];
    const int t = threadIdx.x;
    const int wave = t >> 6;
    const int lane = t & 63;
    float s = 0.0f;
    #pragma unroll
    for (int i = 0; i < (B_SZ / 16) / 256; ++i) s += partials[i * 256 + t];
    #pragma unroll
    for (int off = 32; off; off >>= 1) s += __shfl_down(s, off, 64);
    if (lane == 0) red[wave] = s;
    __syncthreads();
    if (t == 0)
        *loss_slot = (red[0] + red[1] + red[2] + red[3]) * (1.25f / (float)B_SZ);
}

// ---------------------------------------------------------------------------
extern "C" void kernel_launch(void* const* d_in, const int* in_sizes, int n_in,
                              void* d_out, int out_size, void* d_ws, size_t ws_size,
                              hipStream_t stream) {
    const float* x = (const float*)d_in[0];
    const float* codes = (const float*)d_in[1];  // (1, C, D) contiguous

    float* outq = (float*)d_out;                       // [B*D]
    float* out_idx_f = outq + (size_t)B_SZ * D_SZ;     // [B]
    float* loss_slot = out_idx_f + B_SZ;               // [1]

    // workspace: xhi 16M | chi 4M | csq 16K | table 8M (uint2) | partials 4K
    unsigned short* xhi = (unsigned short*)d_ws;
    unsigned short* chi = xhi + (size_t)B_SZ * D_SZ;
    float* csq = (float*)(chi + (size_t)C_SZ * D_SZ);
    uint2* table = (uint2*)(csq + C_SZ);
    float* partials = (float*)(table + (size_t)B_SZ * 64);

    const int XB = (B_SZ * D_SZ) / 4 / 256;           // 8192
    const int CB = C_SZ / 4;                          // 1024
    convert_kernel<<<XB + CB, 256, 0, stream>>>(x, codes, xhi, chi, csq);
    gemm_argmin_kernel<<<dim3(C_SZ / 128, B_SZ / 128), 512, 0, stream>>>(xhi, chi, csq, table);
    rerank_gather_loss_kernel<<<B_SZ / 16, 256, 0, stream>>>(x, codes, csq, table, outq, out_idx_f, partials);
    loss_reduce_kernel<<<1, 256, 0, stream>>>(partials, loss_slot);
}